// Round 1
// baseline (84.646 us; speedup 1.0000x reference)
//
#include <hip/hip_runtime.h>

#define BLOCK 256
#define TPB 4            // true boxes per thread (register ILP)
#define SPLIT_N 32       // N-dimension split for occupancy
#define TILE 256         // pred boxes staged in LDS per tile

__global__ void iou_init_out(float* __restrict__ out, int m) {
    int i = blockIdx.x * blockDim.x + threadIdx.x;
    if (i < m) out[i] = 1.0f;
}

__global__ __launch_bounds__(BLOCK) void iou_max_kernel(
    const float* __restrict__ pred,   // [N,4]
    const float* __restrict__ trub,   // [M,4]
    float* __restrict__ out,          // [M], pre-initialized to 1.0f
    int N, int M)
{
    // this block's pred-chunk [n0, n1)
    const int chunk = (N + gridDim.y - 1) / (int)gridDim.y;
    const int n0 = blockIdx.y * chunk;
    const int n1 = min(N, n0 + chunk);

    __shared__ float4 sbox[TILE];
    __shared__ float  sarea[TILE];

    // ---- load + fix my TPB true boxes into registers ----
    const int jbase = blockIdx.x * (BLOCK * TPB) + threadIdx.x;
    float tx1[TPB], ty1[TPB], tx2[TPB], ty2[TPB], ta[TPB], best[TPB];
#pragma unroll
    for (int t = 0; t < TPB; ++t) {
        int j = jbase + t * BLOCK;
        float4 b = (j < M) ? reinterpret_cast<const float4*>(trub)[j]
                           : make_float4(0.f, 0.f, 0.f, 0.f);
        float x1 = fminf(b.x, b.z), y1 = fminf(b.y, b.w);
        float x2 = fmaxf(b.x, b.z), y2 = fmaxf(b.y, b.w);
        x2 = fmaxf(x2, x1 + 1.0f);  // EPS = 1.0
        y2 = fmaxf(y2, y1 + 1.0f);
        tx1[t] = x1; ty1[t] = y1; tx2[t] = x2; ty2[t] = y2;
        ta[t] = (x2 - x1) * (y2 - y1);
        best[t] = 0.0f;
    }

    // ---- scan pred chunk in LDS tiles ----
    for (int kb = n0; kb < n1; kb += TILE) {
        const int cnt = min(TILE, n1 - kb);
        __syncthreads();
        for (int k = threadIdx.x; k < cnt; k += BLOCK) {
            float4 b = reinterpret_cast<const float4*>(pred)[kb + k];
            float x1 = fminf(b.x, b.z), y1 = fminf(b.y, b.w);
            float x2 = fmaxf(b.x, b.z), y2 = fmaxf(b.y, b.w);
            x2 = fmaxf(x2, x1 + 1.0f);
            y2 = fmaxf(y2, y1 + 1.0f);
            sbox[k]  = make_float4(x1, y1, x2, y2);
            sarea[k] = (x2 - x1) * (y2 - y1);
        }
        __syncthreads();

        for (int k = 0; k < cnt; ++k) {
            float4 p = sbox[k];
            float  pa = sarea[k];
#pragma unroll
            for (int t = 0; t < TPB; ++t) {
                float lx = fmaxf(p.x, tx1[t]);
                float ly = fmaxf(p.y, ty1[t]);
                float rx = fminf(p.z, tx2[t]);
                float ry = fminf(p.w, ty2[t]);
                float w  = fmaxf(rx - lx, 0.0f);
                float h  = fmaxf(ry - ly, 0.0f);
                float inter = w * h;
                float uni   = pa + ta[t] - inter;
                // update best = max(best, inter/uni) without a divide per pair:
                // inter/uni > best  <=>  inter > best*uni   (uni > 0 always, areas >= 1)
                if (inter > best[t] * uni) best[t] = inter / uni;
            }
        }
    }

    // ---- combine partials: out[j] = min over splits of (1 - best) ----
#pragma unroll
    for (int t = 0; t < TPB; ++t) {
        int j = jbase + t * BLOCK;
        if (j < M) {
            float loss = 1.0f - best[t];
            // loss in [0,1]: non-negative floats order like their int bits
            atomicMin(reinterpret_cast<int*>(out) + j, __float_as_int(loss));
        }
    }
}

extern "C" void kernel_launch(void* const* d_in, const int* in_sizes, int n_in,
                              void* d_out, int out_size, void* d_ws, size_t ws_size,
                              hipStream_t stream) {
    const float* pred = (const float*)d_in[0];
    const float* trub = (const float*)d_in[1];
    float* out = (float*)d_out;
    const int N = in_sizes[0] / 4;
    const int M = in_sizes[1] / 4;

    // init out to 1.0f (atomicMin identity for losses in [0,1])
    iou_init_out<<<(M + BLOCK - 1) / BLOCK, BLOCK, 0, stream>>>(out, M);

    dim3 grid((M + BLOCK * TPB - 1) / (BLOCK * TPB), SPLIT_N);
    iou_max_kernel<<<grid, BLOCK, 0, stream>>>(pred, trub, out, N, M);
}

// Round 2
// 49.843 us; speedup vs baseline: 1.6982x; 1.6982x over previous
//
#include <hip/hip_runtime.h>

#define BLOCK 256
#define TPB 4            // true boxes per thread (register ILP)
#define SPLIT_N 128      // N-dimension split: 8 x 128 = 1024 blocks = 4/CU
#define TILE 64          // pred boxes staged in LDS per tile (= N/SPLIT_N)

__global__ void iou_init_out(float* __restrict__ out, int m) {
    int i = blockIdx.x * blockDim.x + threadIdx.x;
    if (i < m) out[i] = 1.0f;
}

__global__ __launch_bounds__(BLOCK) void iou_max_kernel(
    const float* __restrict__ pred,   // [N,4]
    const float* __restrict__ trub,   // [M,4]
    float* __restrict__ out,          // [M], pre-initialized to 1.0f
    int N, int M)
{
    // this block's pred-chunk [n0, n1)
    const int chunk = (N + gridDim.y - 1) / (int)gridDim.y;
    const int n0 = blockIdx.y * chunk;
    const int n1 = min(N, n0 + chunk);

    __shared__ float4 sbox[TILE];
    __shared__ float  sarea[TILE];

    // ---- load + fix my TPB true boxes into registers ----
    const int jbase = blockIdx.x * (BLOCK * TPB) + threadIdx.x;
    float tx1[TPB], ty1[TPB], tx2[TPB], ty2[TPB], ta[TPB], best[TPB];
#pragma unroll
    for (int t = 0; t < TPB; ++t) {
        int j = jbase + t * BLOCK;
        float4 b = (j < M) ? reinterpret_cast<const float4*>(trub)[j]
                           : make_float4(0.f, 0.f, 0.f, 0.f);
        float x1 = fminf(b.x, b.z), y1 = fminf(b.y, b.w);
        float x2 = fmaxf(b.x, b.z), y2 = fmaxf(b.y, b.w);
        x2 = fmaxf(x2, x1 + 1.0f);  // EPS = 1.0
        y2 = fmaxf(y2, y1 + 1.0f);
        tx1[t] = x1; ty1[t] = y1; tx2[t] = x2; ty2[t] = y2;
        ta[t] = (x2 - x1) * (y2 - y1);
        best[t] = 0.0f;
    }

    // ---- scan pred chunk in LDS tiles ----
    for (int kb = n0; kb < n1; kb += TILE) {
        const int cnt = min(TILE, n1 - kb);
        __syncthreads();
        for (int k = threadIdx.x; k < cnt; k += BLOCK) {
            float4 b = reinterpret_cast<const float4*>(pred)[kb + k];
            float x1 = fminf(b.x, b.z), y1 = fminf(b.y, b.w);
            float x2 = fmaxf(b.x, b.z), y2 = fmaxf(b.y, b.w);
            x2 = fmaxf(x2, x1 + 1.0f);
            y2 = fmaxf(y2, y1 + 1.0f);
            sbox[k]  = make_float4(x1, y1, x2, y2);
            sarea[k] = (x2 - x1) * (y2 - y1);
        }
        __syncthreads();

#pragma unroll 4
        for (int k = 0; k < cnt; ++k) {
            float4 p = sbox[k];
            float  pa = sarea[k];
#pragma unroll
            for (int t = 0; t < TPB; ++t) {
                float lx = fmaxf(p.x, tx1[t]);
                float ly = fmaxf(p.y, ty1[t]);
                float rx = fminf(p.z, tx2[t]);
                float ry = fminf(p.w, ty2[t]);
                float w  = fmaxf(rx - lx, 0.0f);
                float h  = fmaxf(ry - ly, 0.0f);
                float inter = w * h;
                float uni   = pa + ta[t] - inter;
                // update best = max(best, inter/uni) without a divide per pair:
                // inter/uni > best  <=>  inter > best*uni   (uni > 0 always, areas >= 1)
                if (inter > best[t] * uni) best[t] = inter / uni;
            }
        }
    }

    // ---- combine partials: out[j] = min over splits of (1 - best) ----
#pragma unroll
    for (int t = 0; t < TPB; ++t) {
        int j = jbase + t * BLOCK;
        if (j < M) {
            float loss = 1.0f - best[t];
            // loss in [0,1]: non-negative floats order like their int bits
            atomicMin(reinterpret_cast<int*>(out) + j, __float_as_int(loss));
        }
    }
}

extern "C" void kernel_launch(void* const* d_in, const int* in_sizes, int n_in,
                              void* d_out, int out_size, void* d_ws, size_t ws_size,
                              hipStream_t stream) {
    const float* pred = (const float*)d_in[0];
    const float* trub = (const float*)d_in[1];
    float* out = (float*)d_out;
    const int N = in_sizes[0] / 4;
    const int M = in_sizes[1] / 4;

    // init out to 1.0f (atomicMin identity for losses in [0,1])
    iou_init_out<<<(M + BLOCK - 1) / BLOCK, BLOCK, 0, stream>>>(out, M);

    dim3 grid((M + BLOCK * TPB - 1) / (BLOCK * TPB), SPLIT_N);
    iou_max_kernel<<<grid, BLOCK, 0, stream>>>(pred, trub, out, N, M);
}

// Round 3
// 45.122 us; speedup vs baseline: 1.8759x; 1.1046x over previous
//
#include <hip/hip_runtime.h>

#define BLOCK 256
#define TPB 8            // true boxes per thread (register ILP, 8 indep chains)
#define SPLIT_N 128      // N-dimension split: 4 x 128 = 512 blocks
#define TILE 64          // pred boxes staged in LDS per tile (= N/SPLIT_N)

__global__ void iou_init_out(float* __restrict__ out, int m) {
    int i = blockIdx.x * blockDim.x + threadIdx.x;
    if (i < m) out[i] = 1.0f;
}

__global__ __launch_bounds__(BLOCK) void iou_max_kernel(
    const float* __restrict__ pred,   // [N,4]
    const float* __restrict__ trub,   // [M,4]
    float* __restrict__ out,          // [M], pre-initialized to 1.0f
    int N, int M)
{
    // this block's pred-chunk [n0, n1)
    const int chunk = (N + gridDim.y - 1) / (int)gridDim.y;
    const int n0 = blockIdx.y * chunk;
    const int n1 = min(N, n0 + chunk);

    __shared__ float4 sbox[TILE];
    __shared__ float  sarea[TILE];

    // ---- load + fix my TPB true boxes into registers ----
    const int jbase = blockIdx.x * (BLOCK * TPB) + threadIdx.x;
    float tx1[TPB], ty1[TPB], tx2[TPB], ty2[TPB], ta[TPB], best[TPB];
#pragma unroll
    for (int t = 0; t < TPB; ++t) {
        int j = jbase + t * BLOCK;
        float4 b = (j < M) ? reinterpret_cast<const float4*>(trub)[j]
                           : make_float4(0.f, 0.f, 0.f, 0.f);
        float x1 = fminf(b.x, b.z), y1 = fminf(b.y, b.w);
        float x2 = fmaxf(b.x, b.z), y2 = fmaxf(b.y, b.w);
        x2 = fmaxf(x2, x1 + 1.0f);  // EPS = 1.0
        y2 = fmaxf(y2, y1 + 1.0f);
        tx1[t] = x1; ty1[t] = y1; tx2[t] = x2; ty2[t] = y2;
        ta[t] = (x2 - x1) * (y2 - y1);
        best[t] = 0.0f;
    }

    // ---- scan pred chunk in LDS tiles ----
    for (int kb = n0; kb < n1; kb += TILE) {
        const int cnt = min(TILE, n1 - kb);
        __syncthreads();
        for (int k = threadIdx.x; k < cnt; k += BLOCK) {
            float4 b = reinterpret_cast<const float4*>(pred)[kb + k];
            float x1 = fminf(b.x, b.z), y1 = fminf(b.y, b.w);
            float x2 = fmaxf(b.x, b.z), y2 = fmaxf(b.y, b.w);
            x2 = fmaxf(x2, x1 + 1.0f);
            y2 = fmaxf(y2, y1 + 1.0f);
            sbox[k]  = make_float4(x1, y1, x2, y2);
            sarea[k] = (x2 - x1) * (y2 - y1);
        }
        __syncthreads();

#pragma unroll 2
        for (int k = 0; k < cnt; ++k) {
            float4 p = sbox[k];
            float  pa = sarea[k];
#pragma unroll
            for (int t = 0; t < TPB; ++t) {
                float lx = fmaxf(p.x, tx1[t]);
                float ly = fmaxf(p.y, ty1[t]);
                float rx = fminf(p.z, tx2[t]);
                float ry = fminf(p.w, ty2[t]);
                float w  = fmaxf(rx - lx, 0.0f);
                float h  = fmaxf(ry - ly, 0.0f);
                float inter = w * h;
                float uni   = (pa + ta[t]) - inter;
                // branchless: uni >= 1 always (EPS forces area >= 1), rcp ~1ulp
                best[t] = fmaxf(best[t], inter * __builtin_amdgcn_rcpf(uni));
            }
        }
    }

    // ---- combine partials: out[j] = min over splits of (1 - best) ----
#pragma unroll
    for (int t = 0; t < TPB; ++t) {
        int j = jbase + t * BLOCK;
        if (j < M) {
            float loss = 1.0f - best[t];
            // loss in [0,1]: non-negative floats order like their int bits
            atomicMin(reinterpret_cast<int*>(out) + j, __float_as_int(loss));
        }
    }
}

extern "C" void kernel_launch(void* const* d_in, const int* in_sizes, int n_in,
                              void* d_out, int out_size, void* d_ws, size_t ws_size,
                              hipStream_t stream) {
    const float* pred = (const float*)d_in[0];
    const float* trub = (const float*)d_in[1];
    float* out = (float*)d_out;
    const int N = in_sizes[0] / 4;
    const int M = in_sizes[1] / 4;

    // init out to 1.0f (atomicMin identity for losses in [0,1])
    iou_init_out<<<(M + BLOCK - 1) / BLOCK, BLOCK, 0, stream>>>(out, M);

    dim3 grid((M + BLOCK * TPB - 1) / (BLOCK * TPB), SPLIT_N);
    iou_max_kernel<<<grid, BLOCK, 0, stream>>>(pred, trub, out, N, M);
}

// Round 4
// 41.368 us; speedup vs baseline: 2.0461x; 1.0907x over previous
//
#include <hip/hip_runtime.h>

#define BLOCK 256
#define TPB 8            // true boxes per thread (8 independent dep chains)
#define SPLIT_N 256      // N-split: 4 x 256 = 1024 blocks = 4 waves/SIMD

// d_ws layout: [0, 128KB) float4 pred_fixed[8192]; [128KB, 160KB) float pred_area[8192]
#define PF_OFF 0
#define PA_OFF (8192 * 16)

// Fix pred boxes into workspace (uniform/scalar side) + init out to 1.0f.
__global__ void fix_and_init(const float* __restrict__ pred,
                             float4* __restrict__ pf,
                             float* __restrict__ pa,
                             float* __restrict__ out,
                             int N, int M) {
    int i = blockIdx.x * blockDim.x + threadIdx.x;
    if (i < N) {
        float4 b = reinterpret_cast<const float4*>(pred)[i];
        float x1 = fminf(b.x, b.z), y1 = fminf(b.y, b.w);
        float x2 = fmaxf(b.x, b.z), y2 = fmaxf(b.y, b.w);
        x2 = fmaxf(x2, x1 + 1.0f);   // EPS = 1.0
        y2 = fmaxf(y2, y1 + 1.0f);
        pf[i] = make_float4(x1, y1, x2, y2);
        pa[i] = (x2 - x1) * (y2 - y1);
    }
    if (i < M) out[i] = 1.0f;        // atomicMin identity (loss in [0,1])
}

__global__ __launch_bounds__(BLOCK) void iou_max_kernel(
    const float4* __restrict__ pf,   // [N] fixed pred boxes (scalar-loaded)
    const float*  __restrict__ pa,   // [N] pred areas
    const float*  __restrict__ trub, // [M,4] raw true boxes
    float* __restrict__ out,         // [M], pre-initialized to 1.0f
    int N, int M)
{
    const int chunk = (N + gridDim.y - 1) / (int)gridDim.y;
    const int n0 = blockIdx.y * chunk;
    const int n1 = min(N, n0 + chunk);

    // ---- load + fix my TPB true boxes into registers ----
    const int jbase = blockIdx.x * (BLOCK * TPB) + threadIdx.x;
    float tx1[TPB], ty1[TPB], tx2[TPB], ty2[TPB], ta[TPB], best[TPB];
#pragma unroll
    for (int t = 0; t < TPB; ++t) {
        int j = jbase + t * BLOCK;
        float4 b = (j < M) ? reinterpret_cast<const float4*>(trub)[j]
                           : make_float4(0.f, 0.f, 0.f, 0.f);
        float x1 = fminf(b.x, b.z), y1 = fminf(b.y, b.w);
        float x2 = fmaxf(b.x, b.z), y2 = fmaxf(b.y, b.w);
        x2 = fmaxf(x2, x1 + 1.0f);
        y2 = fmaxf(y2, y1 + 1.0f);
        tx1[t] = x1; ty1[t] = y1; tx2[t] = x2; ty2[t] = y2;
        ta[t] = (x2 - x1) * (y2 - y1);
        best[t] = 0.0f;
    }

    // ---- scan pred chunk: uniform index -> scalar loads, no LDS, no barriers ----
#pragma unroll 4
    for (int k = n0; k < n1; ++k) {
        float4 p  = pf[k];   // uniform -> s_load_dwordx4 (SGPR broadcast)
        float  par = pa[k];  // uniform -> s_load_dword
#pragma unroll
        for (int t = 0; t < TPB; ++t) {
            float lx = fmaxf(p.x, tx1[t]);
            float ly = fmaxf(p.y, ty1[t]);
            float rx = fminf(p.z, tx2[t]);
            float ry = fminf(p.w, ty2[t]);
            float w  = fmaxf(rx - lx, 0.0f);
            float h  = fmaxf(ry - ly, 0.0f);
            float inter = w * h;
            float uni   = (par + ta[t]) - inter;
            // branchless: uni >= 1 always (EPS forces area >= 1); v_rcp_f32 ~1ulp
            best[t] = fmaxf(best[t], inter * __builtin_amdgcn_rcpf(uni));
        }
    }

    // ---- combine partials: out[j] = min over splits of (1 - best) ----
#pragma unroll
    for (int t = 0; t < TPB; ++t) {
        int j = jbase + t * BLOCK;
        if (j < M) {
            float loss = 1.0f - best[t];
            // loss in [0,1]: non-negative floats order like their int bits
            atomicMin(reinterpret_cast<int*>(out) + j, __float_as_int(loss));
        }
    }
}

extern "C" void kernel_launch(void* const* d_in, const int* in_sizes, int n_in,
                              void* d_out, int out_size, void* d_ws, size_t ws_size,
                              hipStream_t stream) {
    const float* pred = (const float*)d_in[0];
    const float* trub = (const float*)d_in[1];
    float* out = (float*)d_out;
    const int N = in_sizes[0] / 4;
    const int M = in_sizes[1] / 4;

    float4* pf = (float4*)((char*)d_ws + PF_OFF);
    float*  pa = (float*)((char*)d_ws + PA_OFF);

    int mx = max(N, M);
    fix_and_init<<<(mx + BLOCK - 1) / BLOCK, BLOCK, 0, stream>>>(pred, pf, pa, out, N, M);

    dim3 grid((M + BLOCK * TPB - 1) / (BLOCK * TPB), SPLIT_N);
    iou_max_kernel<<<grid, BLOCK, 0, stream>>>(pf, pa, trub, out, N, M);
}